// Round 10
// baseline (11531.012 us; speedup 1.0000x reference)
//
#include <hip/hip_runtime.h>
#include <hip/hip_bf16.h>

typedef short bf16x8 __attribute__((ext_vector_type(8)));
typedef float fx4 __attribute__((ext_vector_type(4)));
typedef unsigned short u16;
typedef u16 u16x4 __attribute__((ext_vector_type(4)));
typedef unsigned u32;

#define TT 512
#define BB 64
#define II 256
#define HH 512
#define OO 256
#define NSTREAM 4
#define WGS_PER_STREAM 16
#define GRID_WG (NSTREAM * WGS_PER_STREAM)   // 64
#define EXS (16 * 512)          // u32 per (stream,parity) block
#define EXP (NSTREAM * EXS)     // u32 per parity

__device__ __forceinline__ u16 f2bf(float f) {
    union { float f; unsigned u; } v; v.f = f;
    unsigned r = v.u + 0x7fffu + ((v.u >> 16) & 1u);
    return (u16)(r >> 16);
}

__device__ __forceinline__ float fsig(float x) {
    return 1.0f / (1.0f + exp2f(x * -1.4426950408889634f));
}
__device__ __forceinline__ float ftanh(float x) {
    return 2.0f * fsig(2.0f * x) - 1.0f;
}

// ---------------- prep: bf16 conversions + tagged-buffer init ----------------
__global__ void prep_kernel(const float* __restrict__ X, const float* __restrict__ Whq,
                            const float* __restrict__ Wxi, const float* __restrict__ Wxf,
                            const float* __restrict__ Wxo, const float* __restrict__ Wxg,
                            const float* __restrict__ Whi, const float* __restrict__ Whf,
                            const float* __restrict__ Who, const float* __restrict__ Whg,
                            u16* __restrict__ Xb, u16* __restrict__ WqT,
                            u16* __restrict__ Wcat, u32* __restrict__ Ex) {
    long gid = (long)blockIdx.x * blockDim.x + threadIdx.x;
    long stride = (long)gridDim.x * blockDim.x;
    const float4* X4 = (const float4*)X;
    for (long i = gid; i < 2097152; i += stride) {
        float4 v = X4[i];
        u16x4 o;
        o.x = f2bf(v.x); o.y = f2bf(v.y); o.z = f2bf(v.z); o.w = f2bf(v.w);
        ((u16x4*)Xb)[i] = o;
    }
    for (long i = gid; i < 131072; i += stride) {
        int o = (int)(i >> 9), k = (int)(i & 511);
        WqT[i] = f2bf(Whq[(long)k * 256 + o]);
    }
    // WcatT: 2048 * 768
    for (long i = gid; i < 1572864; i += stride) {
        int j = (int)(i / 768), k = (int)(i - (long)j * 768);
        int cc = j & 15, tg = j >> 4;
        int gate = cc >> 2;
        int h = tg * 4 + (cc & 3);
        const float* W;
        if (k < II) W = (gate == 0) ? Wxi : (gate == 1) ? Wxf : (gate == 2) ? Wxo : Wxg;
        else        W = (gate == 0) ? Whi : (gate == 1) ? Whf : (gate == 2) ? Who : Whg;
        int kk = (k < II) ? k : k - II;
        Wcat[i] = f2bf(W[(long)kk * HH + h]);
    }
    // Tagged H exchange: parity 0 = {payload 0, tag 0}  (H_0 = 0, step 0 reads
    // tag 0 -> immediately satisfied). parity 1 = tag 0xFFFF (never expected).
    for (long i = gid; i < EXP; i += stride) Ex[i] = 0u;
    for (long i = gid; i < EXP; i += stride) Ex[EXP + i] = 0x0000FFFFu;
}

// ---------------- recurrence: tagged lock-free dataflow ----------------
// 4 independent streams (16 batch rows each) x 16 WGs; member m owns h-cols
// [m*32, m*32+32); per wave two 16-col MFMA tiles, K=768 weights in regs.
//
// NO barriers / flags / fences in the loop. H is exchanged as self-
// describing words:  u32 = bf16(payload)<<16 | step_tag.
//   producer: one relaxed agent-scope atomic u32 store per H element
//             (single-copy atomic -> no tearing; proven-coherent primitive).
//   consumer: relaxed agent-scope atomic loads, spin until tag == t.
// Parity double-buffer makes tag equality safe: a parity-p word can only
// step t-2 -> t -> t+2, and t+2 cannot be written until every peer has
// data-dependently consumed t (its publish depends on its reads).
__global__ __launch_bounds__(256, 1)
void lstm_rec(const u16* __restrict__ Xb, u32* __restrict__ Ex,
              const u16* __restrict__ Wcat,
              const float* __restrict__ bi, const float* __restrict__ bf_,
              const float* __restrict__ bo, const float* __restrict__ bg,
              float* __restrict__ Hs, float* __restrict__ Cs) {
    const int s    = blockIdx.x >> 4;     // stream 0..3
    const int m    = blockIdx.x & 15;     // member 0..15
    const int tid  = threadIdx.x;
    const int lane = tid & 63;
    const int wave = tid >> 6;
    const int c    = lane & 15;
    const int hi4  = lane >> 4;           // 0..3
    const int gate = c >> 2;
    const int hloc = c & 3;

    const int t0 = m * 8 + wave * 2;      // col-tiles 0..127
    const int t1 = t0 + 1;
    const int h0 = t0 * 4 + hloc;
    const int h1 = t1 * 4 + hloc;

    const float* bp = (gate == 0) ? bi : (gate == 1) ? bf_ : (gate == 2) ? bo : bg;
    const float bias0 = bp[h0];
    const float bias1 = bp[h1];

    // ---- preload both col-tiles' B fragments (K=768) into registers ----
    bf16x8 B0[24], B1[24];
#pragma unroll
    for (int kt = 0; kt < 24; ++kt) {
        B0[kt] = *(const bf16x8*)(Wcat + (long)(t0 * 16 + c) * 768 + kt * 32 + hi4 * 8);
        B1[kt] = *(const bf16x8*)(Wcat + (long)(t1 * 16 + c) * 768 + kt * 32 + hi4 * 8);
    }

    const int srcbase = (lane & 48) | hloc;
    const int cbase = c * 512 + hi4 * 8;          // consumer u32 base in block

    // ---- preload X fragments for t=0 ----
    bf16x8 xf[8];
    {
        const u16* xp = Xb + ((long)(s * 16 + c)) * II + hi4 * 8;
#pragma unroll
        for (int kt = 0; kt < 8; ++kt) xf[kt] = *(const bf16x8*)(xp + kt * 32);
    }

    float cst0[4] = {0.f, 0.f, 0.f, 0.f};
    float cst1[4] = {0.f, 0.f, 0.f, 0.f};

    for (int t = 0; t < TT; ++t) {
        const u32 ttag = (u32)t;
        const u32* exR = Ex + (t & 1) * EXP + s * EXS;

        // 1. issue BOTH halves of the tagged H reads (128 pipelined LLC loads)
        u32 w0[64], w1[64];
#pragma unroll
        for (int q = 0; q < 64; ++q)
            w0[q] = __hip_atomic_load(exR + cbase + (q >> 3) * 32 + (q & 7),
                                      __ATOMIC_RELAXED, __HIP_MEMORY_SCOPE_AGENT);
#pragma unroll
        for (int q = 0; q < 64; ++q)
            w1[q] = __hip_atomic_load(exR + cbase + 256 + (q >> 3) * 32 + (q & 7),
                                      __ATOMIC_RELAXED, __HIP_MEMORY_SCOPE_AGENT);

        // 2. X-part MFMAs (registers only — overlap the H-load latency)
        fx4 a00 = {bias0, bias0, bias0, bias0};
        fx4 a01 = {0.f, 0.f, 0.f, 0.f};
        fx4 a10 = {bias1, bias1, bias1, bias1};
        fx4 a11 = {0.f, 0.f, 0.f, 0.f};
#pragma unroll
        for (int kt = 0; kt < 8; ++kt) {
            if (kt & 1) {
                a01 = __builtin_amdgcn_mfma_f32_16x16x32_bf16(xf[kt], B0[kt], a01, 0, 0, 0);
                a11 = __builtin_amdgcn_mfma_f32_16x16x32_bf16(xf[kt], B1[kt], a11, 0, 0, 0);
            } else {
                a00 = __builtin_amdgcn_mfma_f32_16x16x32_bf16(xf[kt], B0[kt], a00, 0, 0, 0);
                a10 = __builtin_amdgcn_mfma_f32_16x16x32_bf16(xf[kt], B1[kt], a10, 0, 0, 0);
            }
        }

        // 3. prefetch next step's X tile
        bf16x8 xf2[8];
        if (t < TT - 1) {
            const u16* xp = Xb + ((long)((t + 1) * BB + s * 16 + c)) * II + hi4 * 8;
#pragma unroll
            for (int kt = 0; kt < 8; ++kt) xf2[kt] = *(const bf16x8*)(xp + kt * 32);
        }

        // 4a. poll half 0 (reload only mismatched words), then MFMA it
        for (;;) {
            bool anybad = false;
#pragma unroll
            for (int q = 0; q < 64; ++q) {
                if (((w0[q] ^ ttag) & 0xffffu) != 0u) {
                    anybad = true;
                    w0[q] = __hip_atomic_load(exR + cbase + (q >> 3) * 32 + (q & 7),
                                              __ATOMIC_RELAXED, __HIP_MEMORY_SCOPE_AGENT);
                }
            }
            if (!__any(anybad)) break;
        }
#pragma unroll
        for (int kt = 0; kt < 8; ++kt) {
            bf16x8 f;
#pragma unroll
            for (int j = 0; j < 8; ++j) f[j] = (short)(w0[kt * 8 + j] >> 16);
            if (kt & 1) {
                a01 = __builtin_amdgcn_mfma_f32_16x16x32_bf16(f, B0[8 + kt], a01, 0, 0, 0);
                a11 = __builtin_amdgcn_mfma_f32_16x16x32_bf16(f, B1[8 + kt], a11, 0, 0, 0);
            } else {
                a00 = __builtin_amdgcn_mfma_f32_16x16x32_bf16(f, B0[8 + kt], a00, 0, 0, 0);
                a10 = __builtin_amdgcn_mfma_f32_16x16x32_bf16(f, B1[8 + kt], a10, 0, 0, 0);
            }
        }

        // 4b. poll half 1, then MFMA it
        for (;;) {
            bool anybad = false;
#pragma unroll
            for (int q = 0; q < 64; ++q) {
                if (((w1[q] ^ ttag) & 0xffffu) != 0u) {
                    anybad = true;
                    w1[q] = __hip_atomic_load(exR + cbase + 256 + (q >> 3) * 32 + (q & 7),
                                              __ATOMIC_RELAXED, __HIP_MEMORY_SCOPE_AGENT);
                }
            }
            if (!__any(anybad)) break;
        }
#pragma unroll
        for (int kt = 0; kt < 8; ++kt) {
            bf16x8 f;
#pragma unroll
            for (int j = 0; j < 8; ++j) f[j] = (short)(w1[kt * 8 + j] >> 16);
            if (kt & 1) {
                a01 = __builtin_amdgcn_mfma_f32_16x16x32_bf16(f, B0[16 + kt], a01, 0, 0, 0);
                a11 = __builtin_amdgcn_mfma_f32_16x16x32_bf16(f, B1[16 + kt], a11, 0, 0, 0);
            } else {
                a00 = __builtin_amdgcn_mfma_f32_16x16x32_bf16(f, B0[16 + kt], a00, 0, 0, 0);
                a10 = __builtin_amdgcn_mfma_f32_16x16x32_bf16(f, B1[16 + kt], a10, 0, 0, 0);
            }
        }
        fx4 accA = a00 + a01;
        fx4 accB = a10 + a11;

        // 5. gather gate preacts + elementwise gate math
        float cnA[4], hnA[4], cnB[4], hnB[4];
#pragma unroll
        for (int r = 0; r < 4; ++r) {
            float pi = __shfl(accA[r], srcbase + 0);
            float pf = __shfl(accA[r], srcbase + 4);
            float po = __shfl(accA[r], srcbase + 8);
            float pg = __shfl(accA[r], srcbase + 12);
            float ig = fsig(pi), fg = fsig(pf), og = fsig(po), gg = ftanh(pg);
            float cv = fg * cst0[r] + ig * gg;
            cst0[r] = cv; cnA[r] = cv;
            hnA[r] = og * ftanh(cv);
        }
#pragma unroll
        for (int r = 0; r < 4; ++r) {
            float pi = __shfl(accB[r], srcbase + 0);
            float pf = __shfl(accB[r], srcbase + 4);
            float po = __shfl(accB[r], srcbase + 8);
            float pg = __shfl(accB[r], srcbase + 12);
            float ig = fsig(pi), fg = fsig(pf), og = fsig(po), gg = ftanh(pg);
            float cv = fg * cst1[r] + ig * gg;
            cst1[r] = cv; cnB[r] = cv;
            hnB[r] = og * ftanh(cv);
        }

        // 6. publish H_{t+1} as tagged words FIRST (critical path: peers wait)
        if (t < TT - 1 && c < 4) {
            u32* exW = Ex + ((t + 1) & 1) * EXP + s * EXS;
            const u32 ntag = (u32)(t + 1);
#pragma unroll
            for (int r = 0; r < 4; ++r) {
                int row = hi4 * 4 + r;
                __hip_atomic_store(exW + row * 512 + h0,
                                   ((u32)f2bf(hnA[r]) << 16) | ntag,
                                   __ATOMIC_RELAXED, __HIP_MEMORY_SCOPE_AGENT);
                __hip_atomic_store(exW + row * 512 + h1,
                                   ((u32)f2bf(hnB[r]) << 16) | ntag,
                                   __ATOMIC_RELAXED, __HIP_MEMORY_SCOPE_AGENT);
            }
        }

        // 7. Hs/Cs fp32 stores — off the critical path, nontemporal
        if (c < 4) {
            float* HsT = Hs + (long)t * BB * HH + (long)(s * 16 + hi4 * 4) * HH;
            float* CsT = Cs + (long)t * BB * HH + (long)(s * 16 + hi4 * 4) * HH;
#pragma unroll
            for (int r = 0; r < 4; ++r) {
                __builtin_nontemporal_store(hnA[r], &HsT[(long)r * HH + h0]);
                __builtin_nontemporal_store(cnA[r], &CsT[(long)r * HH + h0]);
                __builtin_nontemporal_store(hnB[r], &HsT[(long)r * HH + h1]);
                __builtin_nontemporal_store(cnB[r], &CsT[(long)r * HH + h1]);
            }
        }

        // rotate X prefetch (no barriers, no flags — waves run free)
        if (t < TT - 1) {
#pragma unroll
            for (int kt = 0; kt < 8; ++kt) xf[kt] = xf2[kt];
        }
    }
}

// ---------------- output GEMM: out = Hs @ WqT^T + bq ----------------
__global__ __launch_bounds__(256) void outgemm(const float* __restrict__ Hs,
                                               const u16* __restrict__ WqT,
                                               const float* __restrict__ bq,
                                               float* __restrict__ outp) {
    const int lane = threadIdx.x & 63, wave = threadIdx.x >> 6;
    const int cl = lane & 15, hi4 = lane >> 4;
    const int rowbase = blockIdx.x * 64 + wave * 16;
    const int colbase = blockIdx.y * 64;

    const float* Ap = Hs + (long)(rowbase + cl) * HH + hi4 * 8;
    fx4 acc[4];
#pragma unroll
    for (int n = 0; n < 4; ++n) acc[n] = (fx4){0.f, 0.f, 0.f, 0.f};

#pragma unroll
    for (int kt = 0; kt < 16; ++kt) {
        const float4* a4 = (const float4*)(Ap + kt * 32);
        float4 a0 = a4[0], a1 = a4[1];
        bf16x8 af;
        af[0] = (short)f2bf(a0.x); af[1] = (short)f2bf(a0.y);
        af[2] = (short)f2bf(a0.z); af[3] = (short)f2bf(a0.w);
        af[4] = (short)f2bf(a1.x); af[5] = (short)f2bf(a1.y);
        af[6] = (short)f2bf(a1.z); af[7] = (short)f2bf(a1.w);
#pragma unroll
        for (int n = 0; n < 4; ++n) {
            bf16x8 bfg = *(const bf16x8*)(WqT + (long)(colbase + n * 16 + cl) * HH + kt * 32 + hi4 * 8);
            acc[n] = __builtin_amdgcn_mfma_f32_16x16x32_bf16(af, bfg, acc[n], 0, 0, 0);
        }
    }
#pragma unroll
    for (int n = 0; n < 4; ++n) {
        int col = colbase + n * 16 + cl;
        float bv = bq[col];
#pragma unroll
        for (int r = 0; r < 4; ++r) {
            int row = rowbase + hi4 * 4 + r;
            outp[(long)row * OO + col] = acc[n][r] + bv;
        }
    }
}

extern "C" void kernel_launch(void* const* d_in, const int* in_sizes, int n_in,
                              void* d_out, int out_size, void* d_ws, size_t ws_size,
                              hipStream_t stream) {
    const float* X   = (const float*)d_in[0];
    const float* Wxi = (const float*)d_in[1];
    const float* Wxf = (const float*)d_in[2];
    const float* Wxo = (const float*)d_in[3];
    const float* Wxg = (const float*)d_in[4];
    const float* Whi = (const float*)d_in[5];
    const float* Whf = (const float*)d_in[6];
    const float* Who = (const float*)d_in[7];
    const float* Whg = (const float*)d_in[8];
    const float* bi  = (const float*)d_in[9];
    const float* bf_ = (const float*)d_in[10];
    const float* bo  = (const float*)d_in[11];
    const float* bg  = (const float*)d_in[12];
    const float* Whq = (const float*)d_in[13];
    const float* bq  = (const float*)d_in[14];

    float* outp = (float*)d_out;
    float* Hs = outp + (size_t)TT * BB * OO;          // 8388608
    float* Cs = Hs   + (size_t)TT * BB * HH;          // +16777216

    u16* Xb   = (u16*)d_ws;                           // 8388608 u16
    u16* WqT  = Xb + (size_t)TT * BB * II;            // 131072 u16
    u16* Wcat = WqT + (size_t)OO * HH;                // 1572864 u16
    u32* Ex   = (u32*)(Wcat + (size_t)2048 * 768);    // 65536 u32 tagged words

    prep_kernel<<<2048, 256, 0, stream>>>(X, Whq, Wxi, Wxf, Wxo, Wxg,
                                          Whi, Whf, Who, Whg,
                                          Xb, WqT, Wcat, Ex);

    lstm_rec<<<dim3(GRID_WG), dim3(256), 0, stream>>>(
        Xb, Ex, Wcat, bi, bf_, bo, bg, Hs, Cs);

    outgemm<<<dim3(512, 4), 256, 0, stream>>>(Hs, WqT, bq, outp);
}

// Round 11
// 2329.007 us; speedup vs baseline: 4.9510x; 4.9510x over previous
//
#include <hip/hip_runtime.h>
#include <hip/hip_bf16.h>

typedef short bf16x8 __attribute__((ext_vector_type(8)));
typedef float fx4 __attribute__((ext_vector_type(4)));
typedef unsigned short u16;
typedef u16 u16x4 __attribute__((ext_vector_type(4)));
typedef unsigned u32;
typedef unsigned long long u64;

#define TT 512
#define BB 64
#define II 256
#define HH 512
#define OO 256
#define NSTREAM 4
#define WGS_PER_STREAM 16
#define GRID_WG (NSTREAM * WGS_PER_STREAM)   // 64

__device__ __forceinline__ u16 f2bf(float f) {
    union { float f; unsigned u; } v; v.f = f;
    unsigned r = v.u + 0x7fffu + ((v.u >> 16) & 1u);
    return (u16)(r >> 16);
}

__device__ __forceinline__ float fsig(float x) {
    return 1.0f / (1.0f + exp2f(x * -1.4426950408889634f));
}
__device__ __forceinline__ float ftanh(float x) {
    return 2.0f * fsig(2.0f * x) - 1.0f;
}

// ---------------- prep: bf16 conversions + zero init ----------------
__global__ void prep_kernel(const float* __restrict__ X, const float* __restrict__ Whq,
                            const float* __restrict__ Wxi, const float* __restrict__ Wxf,
                            const float* __restrict__ Wxo, const float* __restrict__ Wxg,
                            const float* __restrict__ Whi, const float* __restrict__ Whf,
                            const float* __restrict__ Who, const float* __restrict__ Whg,
                            u16* __restrict__ Xb, u16* __restrict__ WqT,
                            u16* __restrict__ Wcat, u16* __restrict__ Ex,
                            int* __restrict__ cnt) {
    long gid = (long)blockIdx.x * blockDim.x + threadIdx.x;
    long stride = (long)gridDim.x * blockDim.x;
    const float4* X4 = (const float4*)X;
    for (long i = gid; i < 2097152; i += stride) {
        float4 v = X4[i];
        u16x4 o;
        o.x = f2bf(v.x); o.y = f2bf(v.y); o.z = f2bf(v.z); o.w = f2bf(v.w);
        ((u16x4*)Xb)[i] = o;
    }
    for (long i = gid; i < 131072; i += stride) {
        int o = (int)(i >> 9), k = (int)(i & 511);
        WqT[i] = f2bf(Whq[(long)k * 256 + o]);
    }
    // WcatT: 2048 * 768 (col-major-by-gate-tile concatenated weights)
    for (long i = gid; i < 1572864; i += stride) {
        int j = (int)(i / 768), k = (int)(i - (long)j * 768);
        int cc = j & 15, tg = j >> 4;
        int gate = cc >> 2;
        int h = tg * 4 + (cc & 3);
        const float* W;
        if (k < II) W = (gate == 0) ? Wxi : (gate == 1) ? Wxf : (gate == 2) ? Wxo : Wxg;
        else        W = (gate == 0) ? Whi : (gate == 1) ? Whf : (gate == 2) ? Who : Whg;
        int kk = (k < II) ? k : k - II;
        Wcat[i] = f2bf(W[(long)kk * HH + h]);
    }
    // zero H exchange (2 parities x 4 streams x 16 x 512 bf16 = 32768 u32)
    for (long i = gid; i < 32768; i += stride) ((int*)Ex)[i] = 0;
    // zero arrival counters (4 streams x 32-int pad)
    if (gid < 128) cnt[gid] = 0;
}

// ---------------- recurrence: 4 streams x 16 WGs, LDS-staged exchange -------
// Stream s owns batch rows [s*16,s*16+16); member m owns h-cols [m*32,m*32+32);
// per wave two 16-col MFMA tiles over K=768, weights register-resident.
// Per step:
//   consume: per-wave lane0 polls stream counter >= 16*t (relaxed agent load,
//            proven r3/r5/r8/r9) -> each wave bulk-loads a DISJOINT 4-row H
//            slice (8 x u64 relaxed agent atomic loads, coalesced; proven r9)
//            -> ds_write (swizzled) -> __syncthreads -> all waves ds_read_b128
//            fragments. 4x less LLC traffic than r9, zero redundancy.
//   produce: packed-u32 relaxed agent atomic stores (proven r8/r9) ->
//            __syncthreads (drains all waves' vmcnt => stores ACKed at LLC)
//            -> tid0 fetch_add on the stream counter (monotonic, no reset).
// Overwrite race impossible: a WG's Ex reads for step t happen before its own
// step-t increment; peers can only reach step t+1's writes after ALL
// increments for step t (same parity reused only at t+2).
__global__ __launch_bounds__(256, 1)
void lstm_rec(const u16* __restrict__ Xb, u16* __restrict__ Ex, int* __restrict__ cnt,
              const u16* __restrict__ Wcat,
              const float* __restrict__ bi, const float* __restrict__ bf_,
              const float* __restrict__ bo, const float* __restrict__ bg,
              float* __restrict__ Hs, float* __restrict__ Cs) {
    const int s    = blockIdx.x >> 4;     // stream 0..3
    const int m    = blockIdx.x & 15;     // member 0..15
    const int tid  = threadIdx.x;
    const int lane = tid & 63;
    const int wave = tid >> 6;
    const int c    = lane & 15;
    const int hi4  = lane >> 4;           // 0..3
    const int gate = c >> 2;
    const int hloc = c & 3;

    const int t0 = m * 8 + wave * 2;      // col-tiles 0..127
    const int t1 = t0 + 1;
    const int h0 = t0 * 4 + hloc;
    const int h1 = t1 * 4 + hloc;

    const float* bp = (gate == 0) ? bi : (gate == 1) ? bf_ : (gate == 2) ? bo : bg;
    const float bias0 = bp[h0];
    const float bias1 = bp[h1];

    // ---- preload both col-tiles' B fragments (K=768) into registers ----
    bf16x8 B0[24], B1[24];
#pragma unroll
    for (int kt = 0; kt < 24; ++kt) {
        B0[kt] = *(const bf16x8*)(Wcat + (long)(t0 * 16 + c) * 768 + kt * 32 + hi4 * 8);
        B1[kt] = *(const bf16x8*)(Wcat + (long)(t1 * 16 + c) * 768 + kt * 32 + hi4 * 8);
    }

    const int srcbase = (lane & 48) | hloc;

    // LDS H tile: [16 rows][512 cols] bf16, 16B-slot swizzle within rows
    __shared__ u16 Hlds[16 * 512];

    // loader geometry: wave w handles rows [w*4, w*4+4); lane covers
    // i = wave*512 + q*64 + lane (u64 units), q = 0..7
    //   row = wave*4 + (q>>1), colB = (q&1)*512 + lane*8
    // fragment read: row c, byte = c*1024 + ((kt*64 + hi4*16) ^ ((c&7)<<4))
    const int rdswz = (c & 7) << 4;

    int* scnt = cnt + s * 32;

    // ---- preload X fragments for t=0 ----
    bf16x8 xf[8];
    {
        const u16* xp = Xb + ((long)(s * 16 + c)) * II + hi4 * 8;
#pragma unroll
        for (int kt = 0; kt < 8; ++kt) xf[kt] = *(const bf16x8*)(xp + kt * 32);
    }

    float cst0[4] = {0.f, 0.f, 0.f, 0.f};
    float cst1[4] = {0.f, 0.f, 0.f, 0.f};

    for (int t = 0; t < TT; ++t) {
        // 1. per-wave poll: stream counter reaches 16*t when all peers
        //    published H_t (t=0 trivially satisfied; H_0 pre-zeroed)
        if (lane == 0) {
            while (__hip_atomic_load(scnt, __ATOMIC_RELAXED, __HIP_MEMORY_SCOPE_AGENT) < 16 * t)
                __builtin_amdgcn_s_sleep(2);
        }
        __builtin_amdgcn_sched_barrier(0);   // loads must not hoist above poll

        // 2. bulk-load this wave's disjoint 4-row slice (coalesced u64 sc1)
        u64 hbuf[8];
        {
            const u64* eq = (const u64*)(Ex + ((t & 1) * NSTREAM + s) * 8192);
            const int ibase = wave * 512 + lane;
#pragma unroll
            for (int q = 0; q < 8; ++q)
                hbuf[q] = __hip_atomic_load(eq + ibase + q * 64,
                                            __ATOMIC_RELAXED, __HIP_MEMORY_SCOPE_AGENT);
        }
        // 3. stage to LDS (swizzled 16B slots)
#pragma unroll
        for (int q = 0; q < 8; ++q) {
            int row = wave * 4 + (q >> 1);
            int colB = (q & 1) * 512 + lane * 8;
            int b = row * 1024 + (colB ^ ((row & 7) << 4));
            *(u64*)&Hlds[b >> 1] = hbuf[q];
        }
        __syncthreads();

        // 4. read fragments + MFMAs (ds_read first for latency, X overlaps)
        bf16x8 hf[16];
#pragma unroll
        for (int kt = 0; kt < 16; ++kt) {
            int b = c * 1024 + ((kt * 64 + hi4 * 16) ^ rdswz);
            hf[kt] = *(const bf16x8*)&Hlds[b >> 1];
        }

        fx4 a00 = {bias0, bias0, bias0, bias0};
        fx4 a01 = {0.f, 0.f, 0.f, 0.f};
        fx4 a10 = {bias1, bias1, bias1, bias1};
        fx4 a11 = {0.f, 0.f, 0.f, 0.f};
#pragma unroll
        for (int kt = 0; kt < 8; ++kt) {
            if (kt & 1) {
                a01 = __builtin_amdgcn_mfma_f32_16x16x32_bf16(xf[kt], B0[kt], a01, 0, 0, 0);
                a11 = __builtin_amdgcn_mfma_f32_16x16x32_bf16(xf[kt], B1[kt], a11, 0, 0, 0);
            } else {
                a00 = __builtin_amdgcn_mfma_f32_16x16x32_bf16(xf[kt], B0[kt], a00, 0, 0, 0);
                a10 = __builtin_amdgcn_mfma_f32_16x16x32_bf16(xf[kt], B1[kt], a10, 0, 0, 0);
            }
        }
#pragma unroll
        for (int kt = 0; kt < 16; ++kt) {
            if (kt & 1) {
                a01 = __builtin_amdgcn_mfma_f32_16x16x32_bf16(hf[kt], B0[8 + kt], a01, 0, 0, 0);
                a11 = __builtin_amdgcn_mfma_f32_16x16x32_bf16(hf[kt], B1[8 + kt], a11, 0, 0, 0);
            } else {
                a00 = __builtin_amdgcn_mfma_f32_16x16x32_bf16(hf[kt], B0[8 + kt], a00, 0, 0, 0);
                a10 = __builtin_amdgcn_mfma_f32_16x16x32_bf16(hf[kt], B1[8 + kt], a10, 0, 0, 0);
            }
        }
        fx4 accA = a00 + a01;
        fx4 accB = a10 + a11;

        // 5. X prefetch for t+1 (plain cached loads; L2 stays warm)
        bf16x8 xf2[8];
        if (t < TT - 1) {
            const u16* xp = Xb + ((long)((t + 1) * BB + s * 16 + c)) * II + hi4 * 8;
#pragma unroll
            for (int kt = 0; kt < 8; ++kt) xf2[kt] = *(const bf16x8*)(xp + kt * 32);
        }

        // 6. gather gate preacts + elementwise gate math
        float cnA[4], hnA[4], cnB[4], hnB[4];
#pragma unroll
        for (int r = 0; r < 4; ++r) {
            float pi = __shfl(accA[r], srcbase + 0);
            float pf = __shfl(accA[r], srcbase + 4);
            float po = __shfl(accA[r], srcbase + 8);
            float pg = __shfl(accA[r], srcbase + 12);
            float ig = fsig(pi), fg = fsig(pf), og = fsig(po), gg = ftanh(pg);
            float cv = fg * cst0[r] + ig * gg;
            cst0[r] = cv; cnA[r] = cv;
            hnA[r] = og * ftanh(cv);
        }
#pragma unroll
        for (int r = 0; r < 4; ++r) {
            float pi = __shfl(accB[r], srcbase + 0);
            float pf = __shfl(accB[r], srcbase + 4);
            float po = __shfl(accB[r], srcbase + 8);
            float pg = __shfl(accB[r], srcbase + 12);
            float ig = fsig(pi), fg = fsig(pf), og = fsig(po), gg = ftanh(pg);
            float cv = fg * cst1[r] + ig * gg;
            cst1[r] = cv; cnB[r] = cv;
            hnB[r] = og * ftanh(cv);
        }

        if (t < TT - 1) {
            // 7. publish H_{t+1}: packed u32 relaxed agent stores (proven r8/r9)
            u32 pkA[4], pkB[4];
#pragma unroll
            for (int r = 0; r < 4; ++r) {
                float aHi = __shfl(hnA[r], lane | 1);
                float bHi = __shfl(hnB[r], lane | 1);
                pkA[r] = (u32)f2bf(hnA[r]) | ((u32)f2bf(aHi) << 16);
                pkB[r] = (u32)f2bf(hnB[r]) | ((u32)f2bf(bHi) << 16);
            }
            if (c < 4 && (c & 1) == 0) {   // lanes c=0,2 (gate 0, even col)
                u16* exW = Ex + (((t + 1) & 1) * NSTREAM + s) * 8192;
#pragma unroll
                for (int r = 0; r < 4; ++r) {
                    int row = hi4 * 4 + r;
                    __hip_atomic_store((u32*)(exW + row * 512 + h0), pkA[r],
                                       __ATOMIC_RELAXED, __HIP_MEMORY_SCOPE_AGENT);
                    __hip_atomic_store((u32*)(exW + row * 512 + h1), pkB[r],
                                       __ATOMIC_RELAXED, __HIP_MEMORY_SCOPE_AGENT);
                }
            }

            // 8. drain all waves' stores (barrier emits vmcnt(0)), then arrive
            __syncthreads();
            if (tid == 0)
                __hip_atomic_fetch_add(scnt, 1, __ATOMIC_RELAXED, __HIP_MEMORY_SCOPE_AGENT);
        }

        // 9. Hs/Cs fp32 stores — after arrival, plain (L2 write-combines)
        if (c < 4) {
            float* HsT = Hs + (long)t * BB * HH + (long)(s * 16 + hi4 * 4) * HH;
            float* CsT = Cs + (long)t * BB * HH + (long)(s * 16 + hi4 * 4) * HH;
#pragma unroll
            for (int r = 0; r < 4; ++r) {
                HsT[(long)r * HH + h0] = hnA[r];
                CsT[(long)r * HH + h0] = cnA[r];
                HsT[(long)r * HH + h1] = hnB[r];
                CsT[(long)r * HH + h1] = cnB[r];
            }
        }

        // rotate X prefetch
        if (t < TT - 1) {
#pragma unroll
            for (int kt = 0; kt < 8; ++kt) xf[kt] = xf2[kt];
        }
    }
}

// ---------------- output GEMM: out = Hs @ WqT^T + bq ----------------
__global__ __launch_bounds__(256) void outgemm(const float* __restrict__ Hs,
                                               const u16* __restrict__ WqT,
                                               const float* __restrict__ bq,
                                               float* __restrict__ outp) {
    const int lane = threadIdx.x & 63, wave = threadIdx.x >> 6;
    const int cl = lane & 15, hi4 = lane >> 4;
    const int rowbase = blockIdx.x * 64 + wave * 16;
    const int colbase = blockIdx.y * 64;

    const float* Ap = Hs + (long)(rowbase + cl) * HH + hi4 * 8;
    fx4 acc[4];
#pragma unroll
    for (int n = 0; n < 4; ++n) acc[n] = (fx4){0.f, 0.f, 0.f, 0.f};

#pragma unroll
    for (int kt = 0; kt < 16; ++kt) {
        const float4* a4 = (const float4*)(Ap + kt * 32);
        float4 a0 = a4[0], a1 = a4[1];
        bf16x8 af;
        af[0] = (short)f2bf(a0.x); af[1] = (short)f2bf(a0.y);
        af[2] = (short)f2bf(a0.z); af[3] = (short)f2bf(a0.w);
        af[4] = (short)f2bf(a1.x); af[5] = (short)f2bf(a1.y);
        af[6] = (short)f2bf(a1.z); af[7] = (short)f2bf(a1.w);
#pragma unroll
        for (int n = 0; n < 4; ++n) {
            bf16x8 bfg = *(const bf16x8*)(WqT + (long)(colbase + n * 16 + cl) * HH + kt * 32 + hi4 * 8);
            acc[n] = __builtin_amdgcn_mfma_f32_16x16x32_bf16(af, bfg, acc[n], 0, 0, 0);
        }
    }
#pragma unroll
    for (int n = 0; n < 4; ++n) {
        int col = colbase + n * 16 + cl;
        float bv = bq[col];
#pragma unroll
        for (int r = 0; r < 4; ++r) {
            int row = rowbase + hi4 * 4 + r;
            outp[(long)row * OO + col] = acc[n][r] + bv;
        }
    }
}

extern "C" void kernel_launch(void* const* d_in, const int* in_sizes, int n_in,
                              void* d_out, int out_size, void* d_ws, size_t ws_size,
                              hipStream_t stream) {
    const float* X   = (const float*)d_in[0];
    const float* Wxi = (const float*)d_in[1];
    const float* Wxf = (const float*)d_in[2];
    const float* Wxo = (const float*)d_in[3];
    const float* Wxg = (const float*)d_in[4];
    const float* Whi = (const float*)d_in[5];
    const float* Whf = (const float*)d_in[6];
    const float* Who = (const float*)d_in[7];
    const float* Whg = (const float*)d_in[8];
    const float* bi  = (const float*)d_in[9];
    const float* bf_ = (const float*)d_in[10];
    const float* bo  = (const float*)d_in[11];
    const float* bg  = (const float*)d_in[12];
    const float* Whq = (const float*)d_in[13];
    const float* bq  = (const float*)d_in[14];

    float* outp = (float*)d_out;
    float* Hs = outp + (size_t)TT * BB * OO;          // 8388608
    float* Cs = Hs   + (size_t)TT * BB * HH;          // +16777216

    u16* Xb   = (u16*)d_ws;                           // 8388608 u16
    u16* WqT  = Xb + (size_t)TT * BB * II;            // 131072 u16
    u16* Wcat = WqT + (size_t)OO * HH;                // 1572864 u16
    u16* Ex   = Wcat + (size_t)2048 * 768;            // 65536 u16 (2 par x 4 strm)
    int* cnt  = (int*)(Ex + (size_t)65536);           // 128 ints (4 x 32 pad)

    prep_kernel<<<2048, 256, 0, stream>>>(X, Whq, Wxi, Wxf, Wxo, Wxg,
                                          Whi, Whf, Who, Whg,
                                          Xb, WqT, Wcat, Ex, cnt);

    lstm_rec<<<dim3(GRID_WG), dim3(256), 0, stream>>>(
        Xb, Ex, cnt, Wcat, bi, bf_, bo, bg, Hs, Cs);

    outgemm<<<dim3(512, 4), 256, 0, stream>>>(Hs, WqT, bq, outp);
}